// Round 6
// baseline (436.150 us; speedup 1.0000x reference)
//
#include <hip/hip_runtime.h>
#include <math.h>

typedef float f2v __attribute__((ext_vector_type(2)));
typedef float f4v __attribute__((ext_vector_type(4)));

#define NTILE 16
#define FPAD 260
#define TILE_PAD (9 * FPAD)   // 2340 words per padded tile
#define FT 36864              // words per batch (4096*9)

__global__ __launch_bounds__(256) void scorer_kernel(
    const float* __restrict__ x,     // [B, 4096, 9]
    const float* __restrict__ th1,   // [2]
    const float* __restrict__ W1,    // [4096, 32]
    const float* __restrict__ b1,    // [32]
    const float* __restrict__ gamma, // [32]
    const float* __restrict__ beta,  // [32]
    const float* __restrict__ th2,   // [2]
    const float* __restrict__ W2,    // [32]
    const float* __restrict__ b2p,   // [1]
    float* __restrict__ out)         // [B, 9]
{
    // double-buffered transposed tile: buf[k][t][f], f-padded to 260
    __shared__ __align__(16) float xl[2 * TILE_PAD];   // 18720 B
    const int tid = threadIdx.x;
    const int hg  = tid & 3;           // h-octet: h = hg*8 .. hg*8+7
    const int fc  = tid >> 2;          // 0..63: f-rows fc*4 .. fc*4+3
    const int wv  = tid >> 6;          // wave 0..3
    const float* xb = x + (size_t)blockIdx.x * FT;

    f2v acc[9][4];                     // [t][h-pair]: h = hg*8 + q*2 + {0,1}
    #pragma unroll
    for (int t = 0; t < 9; ++t)
        #pragma unroll
        for (int q = 0; q < 4; ++q) acc[t][q] = (f2v){0.f, 0.f};

    // transpose-scatter LDS addresses: flat tile word w -> [t][f]
    int laddr[9];
    #pragma unroll
    for (int j = 0; j < 9; ++j) {
        int w = (j < 4) ? tid * 4 + j
              : (j < 8) ? 1024 + tid * 4 + (j - 4)
                        : 2048 + tid;
        int f = (unsigned)w / 9u;
        int t = w - 9 * f;
        laddr[j] = t * FPAD + f;
    }

    // ---- prologue: coalesced load of tile 0 into regs ----
    f4v s04 = __builtin_nontemporal_load((const f4v*)(xb + tid * 4));
    f4v s47 = __builtin_nontemporal_load((const f4v*)(xb + 1024 + tid * 4));
    float s8 = __builtin_nontemporal_load(xb + 2048 + tid);

    const f4v* __restrict__ W1v = (const f4v*)W1;
    int cur = 0;
    for (int tile = 0; tile < NTILE; ++tile) {
        __syncthreads();   // #1: buf[cur] free; prefetch regs landed
        float* lb = &xl[cur * TILE_PAD];
        lb[laddr[0]] = s04.x; lb[laddr[1]] = s04.y;
        lb[laddr[2]] = s04.z; lb[laddr[3]] = s04.w;
        lb[laddr[4]] = s47.x; lb[laddr[5]] = s47.y;
        lb[laddr[6]] = s47.z; lb[laddr[7]] = s47.w;
        lb[laddr[8]] = s8;
        __syncthreads();   // #2: buf[cur] readable
        // ---- issue next tile's loads; drain happens at next #1 ----
        if (tile + 1 < NTILE) {
            const float* gt = xb + (size_t)(tile + 1) * 2304;
            s04 = __builtin_nontemporal_load((const f4v*)(gt + tid * 4));
            s47 = __builtin_nontemporal_load((const f4v*)(gt + 1024 + tid * 4));
            s8  = __builtin_nontemporal_load(gt + 2048 + tid);
        }
        if (tile == 0) {
            // fold plane_rotate(theta1): global f-rows 0..3
            if (tid < 18) {
                int p = tid / 9, t = tid - p * 9;
                float c = cosf(th1[p]), sn = sinf(th1[p]);
                float a  = xl[t * FPAD + 2 * p];
                float bv = xl[t * FPAD + 2 * p + 1];
                xl[t * FPAD + 2 * p]     = c * a - sn * bv;
                xl[t * FPAD + 2 * p + 1] = sn * a + c * bv;
            }
            __syncthreads();
        }
        // ---- compute: 2 halves x (2 f-rows hoisted, 9 t x b64 x 8 pk) ----
        const float* xbuf = &xl[cur * TILE_PAD];
        const int fb = tile * 256;
        #pragma unroll
        for (int ih = 0; ih < 2; ++ih) {
            const int f0 = fb + fc * 4 + ih * 2;
            f4v wa0 = W1v[(size_t)f0 * 8 + hg * 2];
            f4v wa1 = W1v[(size_t)f0 * 8 + hg * 2 + 1];
            f4v wb0 = W1v[(size_t)(f0 + 1) * 8 + hg * 2];
            f4v wb1 = W1v[(size_t)(f0 + 1) * 8 + hg * 2 + 1];
            const float* xr = xbuf + fc * 4 + ih * 2;
            #pragma unroll
            for (int t = 0; t < 9; ++t) {
                f2v xp = *(const f2v*)(xr + t * FPAD);
                f2v xa = {xp.x, xp.x}, xc = {xp.y, xp.y};
                acc[t][0] += xa * (f2v){wa0.x, wa0.y};
                acc[t][1] += xa * (f2v){wa0.z, wa0.w};
                acc[t][2] += xa * (f2v){wa1.x, wa1.y};
                acc[t][3] += xa * (f2v){wa1.z, wa1.w};
                acc[t][0] += xc * (f2v){wb0.x, wb0.y};
                acc[t][1] += xc * (f2v){wb0.z, wb0.w};
                acc[t][2] += xc * (f2v){wb1.x, wb1.y};
                acc[t][3] += xc * (f2v){wb1.z, wb1.w};
            }
        }
        cur ^= 1;
    }

    // ---- reduce over fc: butterfly xor{4,8,16,32} -> per-wave partials ----
    // red = xl[0..1152): buf0 region; tile 15 read buf1 -> disjoint.
    const int lane = tid & 63;
    float* red = xl;
    #pragma unroll
    for (int t = 0; t < 9; ++t)
        #pragma unroll
        for (int q = 0; q < 4; ++q) {
            f2v v = acc[t][q];
            v.x += __shfl_xor(v.x, 4);  v.y += __shfl_xor(v.y, 4);
            v.x += __shfl_xor(v.x, 8);  v.y += __shfl_xor(v.y, 8);
            v.x += __shfl_xor(v.x, 16); v.y += __shfl_xor(v.y, 16);
            v.x += __shfl_xor(v.x, 32); v.y += __shfl_xor(v.y, 32);
            if (lane < 4)   // lane == hg, fc-sum for this wave
                *(f2v*)&red[(wv * 4 + lane) * 72 + t * 8 + q * 2] = v;
        }
    __syncthreads();

    // ---- cross-wave sum + bias + modular phase norm -> g at xl[1152..) ----
    for (int o = tid; o < 288; o += 256) {
        int t = o >> 5, h = o & 31;
        int hg2 = h >> 3, hh = h & 7;
        int idx = t * 8 + hh;
        float v = red[(0 * 4 + hg2) * 72 + idx]
                + red[(1 * 4 + hg2) * 72 + idx]
                + red[(2 * 4 + hg2) * 72 + idx]
                + red[(3 * 4 + hg2) * 72 + idx];
        v += b1[h];
        float wr = v - 7.0f * floorf(v / 7.0f + 0.5f);
        xl[1152 + o] = gamma[h] * wr + beta[h];   // o == t*32 + h
    }
    __syncthreads();

    // ---- rotate(theta2), dot with W2, bias -> scores ----
    if (tid < 9) {
        const float* g = &xl[1152 + tid * 32];
        float c0 = cosf(th2[0]), s0 = sinf(th2[0]);
        float c1 = cosf(th2[1]), s1 = sinf(th2[1]);
        float sc = (c0 * g[0] - s0 * g[1]) * W2[0]
                 + (s0 * g[0] + c0 * g[1]) * W2[1]
                 + (c1 * g[2] - s1 * g[3]) * W2[2]
                 + (s1 * g[2] + c1 * g[3]) * W2[3];
        #pragma unroll
        for (int h = 4; h < 32; ++h) sc += g[h] * W2[h];
        sc += b2p[0];
        xl[1440 + tid] = sc;
    }
    __syncthreads();

    // ---- softmax over t, write out ----
    if (tid < 9) {
        const float* sb = &xl[1440];
        float m = sb[0];
        #pragma unroll
        for (int k = 1; k < 9; ++k) m = fmaxf(m, sb[k]);
        float den = 0.f;
        #pragma unroll
        for (int k = 0; k < 9; ++k) den += expf(sb[k] - m);
        out[(size_t)blockIdx.x * 9 + tid] = expf(sb[tid] - m) / den;
    }
}

extern "C" void kernel_launch(void* const* d_in, const int* in_sizes, int n_in,
                              void* d_out, int out_size, void* d_ws, size_t ws_size,
                              hipStream_t stream) {
    const float* x     = (const float*)d_in[0];
    const float* th1   = (const float*)d_in[1];
    const float* W1    = (const float*)d_in[2];
    const float* b1    = (const float*)d_in[3];
    const float* gamma = (const float*)d_in[4];
    const float* beta  = (const float*)d_in[5];
    const float* th2   = (const float*)d_in[6];
    const float* W2    = (const float*)d_in[7];
    const float* b2    = (const float*)d_in[8];
    float* out = (float*)d_out;

    const int B = in_sizes[0] / FT;   // 8192
    dim3 grid(B), block(256);
    hipLaunchKernelGGL(scorer_kernel, grid, block, 0, stream,
                       x, th1, W1, b1, gamma, beta, th2, W2, b2, out);
}